// Round 7
// baseline (51.190 us; speedup 1.0000x reference)
//
#include <hip/hip_runtime.h>
#include <math.h>

#define B_SZ 4096
#define D_SZ 32
#define M1_SZ 8
#define H_SZ 64
#define NSTEP 20
#define S1 21
#define BROWS 32   // batch rows per block (4 waves x 8 rows)
#define BT 256     // lane = [hoct(3b) | b_lo(3b)]
#define HO 8       // h values per thread (64 / 8 octants)

#ifndef M_PI
#define M_PI 3.14159265358979323846
#endif

#define LOG2E 1.44269504088896340736f
#define LN2   0.69314718055994530942f

__device__ __forceinline__ float fast_exp2(float x) {
#if __has_builtin(__builtin_amdgcn_exp2f)
  return __builtin_amdgcn_exp2f(x);
#else
  return exp2f(x);
#endif
}
__device__ __forceinline__ float fast_rcp(float x) {
#if __has_builtin(__builtin_amdgcn_rcpf)
  return __builtin_amdgcn_rcpf(x);
#else
  return 1.0f / x;
#endif
}

__global__ __launch_bounds__(BT) void umnn_main_kernel(
    const float* __restrict__ x, const float* __restrict__ x0,
    const float* __restrict__ We, const float* __restrict__ be,
    const float* __restrict__ W1, const float* __restrict__ b1,
    const float* __restrict__ W2, const float* __restrict__ b2,
    const float* __restrict__ scaling, float* __restrict__ out) {
  const int btile = blockIdx.x * BROWS;
  const int d = blockIdx.y;  // block-uniform
  const int tid = threadIdx.x;

  __shared__ float W1t[H_SZ * 13];     // [h][i], i=0..8, stride 13 -> 2-way banks (free)
  __shared__ float b1s[H_SZ];
  __shared__ float W2s[H_SZ];
  __shared__ float Wes[D_SZ * M1_SZ];  // c-major [c][m]
  __shared__ float bes[M1_SZ];
  __shared__ float ccws[S1];
  __shared__ float stepss[S1];
  __shared__ float misc[2];            // b2[d], exp(scaling[d])
  __shared__ float xs[BROWS * 36];     // x tile, row stride 36

  // ---- staging ----
  {
    const float* W1d = W1 + d * (M1_SZ + 1) * H_SZ;  // [i][h] row-major
    for (int idx = tid; idx < (M1_SZ + 1) * H_SZ; idx += BT) {
      int i = idx >> 6, h = idx & 63;  // coalesced global read
      W1t[h * 13 + i] = W1d[idx];      // transposed LDS write
    }
    if (tid < H_SZ) { b1s[tid] = b1[d * H_SZ + tid]; W2s[tid] = W2[d * H_SZ + tid]; }
    if (tid < M1_SZ) bes[tid] = be[tid * D_SZ + d];
    {
      int m = tid >> 5, c = tid & 31;
      Wes[c * M1_SZ + m] = We[(m * D_SZ + d) * D_SZ + c];
    }
    {  // x tile: 32 rows x 32 floats = 256 float4, one per thread
      const float4* xg = reinterpret_cast<const float4*>(x + (size_t)btile * D_SZ);
      int row = tid >> 3, c4 = tid & 7;
      *reinterpret_cast<float4*>(&xs[row * 36 + c4 * 4]) = xg[tid];
    }
    if (tid < S1) {  // fp32 Clenshaw-Curtis (threshold is lenient)
      stepss[tid] = cosf((float)tid * ((float)M_PI / 20.f));
      float acc = 0.f;
#pragma unroll
      for (int k = 0; k <= 10; ++k) {
        float w = (k == 0) ? 1.f : 2.f / (1.f - 4.f * (float)(k * k));
        float c = cosf((float)(k * tid) * ((float)M_PI / 10.f));
        float lam = (tid == 0 || tid == NSTEP) ? 0.5f * c : c;
        acc += w * lam;
      }
      ccws[tid] = 0.1f * acc;
    }
    if (tid == 0) { misc[0] = b2[d]; misc[1] = __expf(scaling[d]); }
  }
  __syncthreads();

  const int lane = tid & 63;
  const int hoct = (lane >> 3) & 7;                  // h-octant 0..7
  const int b_local = ((tid >> 6) << 3) | (lane & 7);
  const int b = btile + b_local;
  const float* xrow = &xs[b_local * 36];

  // ---- masked encoder ----
  float a[M1_SZ];
#pragma unroll
  for (int m = 0; m < M1_SZ; ++m) a[m] = bes[m];
  for (int c = 0; c < d; ++c) {  // wave-uniform trip count
    float xc = xrow[c];
#pragma unroll
    for (int m = 0; m < M1_SZ; ++m) a[m] = fmaf(xc, Wes[c * M1_SZ + m], a[m]);
  }
  float hm[M1_SZ];
#pragma unroll
  for (int m = 0; m < M1_SZ; ++m) {  // tanh via exp2 + rcp
    float t = fast_exp2(a[m] * (2.f * LOG2E));
    hm[m] = 1.f - 2.f * fast_rcp(t + 1.f);
  }
  const float hm0 = hm[0];

  const float xb = xrow[d];
  const float x0b = x0[(size_t)b * D_SZ + d];
  const float dxe = xb - x0b;
  const float xc1 = 0.5f * dxe;
  const float xc1L = xc1 * LOG2E;
  const float xc0L = (x0b + xc1) * LOG2E;

  // ---- preload per-h constants (8 h per thread; ~24 regs, fits 64-reg budget) ----
  float baseL[HO], w1x[HO], w2h[HO];
  float w2sA = 0.f, w2sB = 0.f;
#pragma unroll
  for (int j = 0; j < HO; ++j) {
    const int hh = hoct * HO + j;
    const float* wrow = &W1t[hh * 13];
    float base = b1s[hh];
#pragma unroll
    for (int m = 0; m < M1_SZ; ++m) base = fmaf(hm[m], wrow[m + 1], base);
    baseL[j] = base * LOG2E;
    w1x[j] = wrow[0];
    w2h[j] = W2s[hh];
    if (j & 1) w2sB += w2h[j]; else w2sA += w2h[j];
  }
  const float b2v = misc[0];

  // ---- fused main loop: per step, 8-h partial -> 3-level butterfly -> elu -> dzsum ----
  float dzsum = 0.f;
#pragma unroll 3
  for (int s = 0; s < S1; ++s) {
    const float XsL = fmaf(xc1L, stepss[s], xc0L);
    float accA = -w2sA, accB = -w2sB;  // folds the elu "-1" term
#pragma unroll
    for (int j = 0; j < HO; j += 2) {
      {
        float preL = fmaf(XsL, w1x[j], baseL[j]);
        float e = fmaf(fmaxf(preL, 0.f), LN2, fast_exp2(fminf(preL, 0.f)));
        accA = fmaf(e, w2h[j], accA);
      }
      {
        float preL = fmaf(XsL, w1x[j + 1], baseL[j + 1]);
        float e = fmaf(fmaxf(preL, 0.f), LN2, fast_exp2(fminf(preL, 0.f)));
        accB = fmaf(e, w2h[j + 1], accB);
      }
    }
    float acc = accA + accB;
    acc += __shfl_xor(acc, 8);
    acc += __shfl_xor(acc, 16);
    acc += __shfl_xor(acc, 32);
    acc += b2v;
    float pL = acc * LOG2E;
    float dz = fmaf(fmaxf(pL, 0.f), LN2, fast_exp2(fminf(pL, 0.f)));  // elu+1
    dzsum = fmaf(ccws[s], dz, dzsum);
  }

  float z = fmaf(xc1, dzsum, hm0);  // z_int + z0
  if (hoct == 0) out[(size_t)b * D_SZ + d] = misc[1] * z;
}

extern "C" void kernel_launch(void* const* d_in, const int* in_sizes, int n_in,
                              void* d_out, int out_size, void* d_ws, size_t ws_size,
                              hipStream_t stream) {
  const float* x       = (const float*)d_in[0];
  const float* x0      = (const float*)d_in[1];
  const float* We      = (const float*)d_in[2];
  const float* be      = (const float*)d_in[3];
  const float* W1      = (const float*)d_in[4];
  const float* b1      = (const float*)d_in[5];
  const float* W2      = (const float*)d_in[6];
  const float* b2      = (const float*)d_in[7];
  const float* scaling = (const float*)d_in[8];
  float* out = (float*)d_out;

  dim3 grid(B_SZ / BROWS, D_SZ);
  umnn_main_kernel<<<grid, BT, 0, stream>>>(x, x0, We, be, W1, b1, W2, b2,
                                            scaling, out);
}

// Round 8
// 51.000 us; speedup vs baseline: 1.0037x; 1.0037x over previous
//
#include <hip/hip_runtime.h>
#include <math.h>

#define B_SZ 4096
#define D_SZ 32
#define M1_SZ 8
#define H_SZ 64
#define NSTEP 20
#define S1 21
#define BROWS 32   // batch rows per block (4 waves x 8 rows)
#define BT 256     // lane = [hoct(3b) | b_lo(3b)]
#define HO 8       // h values per thread (64 / 8 octants)

#ifndef M_PI
#define M_PI 3.14159265358979323846
#endif

#define LOG2E 1.44269504088896340736f
#define LN2   0.69314718055994530942f

__device__ __forceinline__ float fast_exp2(float x) {
#if __has_builtin(__builtin_amdgcn_exp2f)
  return __builtin_amdgcn_exp2f(x);
#else
  return exp2f(x);
#endif
}
__device__ __forceinline__ float fast_rcp(float x) {
#if __has_builtin(__builtin_amdgcn_rcpf)
  return __builtin_amdgcn_rcpf(x);
#else
  return 1.0f / x;
#endif
}
// Opaque pin: compiler must keep v live in a VGPR; cannot remat from LDS.
__device__ __forceinline__ void pin(float& v) { asm volatile("" : "+v"(v)); }

__global__ __launch_bounds__(BT) void umnn_main_kernel(
    const float* __restrict__ x, const float* __restrict__ x0,
    const float* __restrict__ We, const float* __restrict__ be,
    const float* __restrict__ W1, const float* __restrict__ b1,
    const float* __restrict__ W2, const float* __restrict__ b2,
    const float* __restrict__ scaling, float* __restrict__ out) {
  const int btile = blockIdx.x * BROWS;
  const int d = blockIdx.y;  // block-uniform
  const int tid = threadIdx.x;

  __shared__ float W1t[H_SZ * 13];     // [h][i], i=0..8, stride 13 -> 2-way banks (free)
  __shared__ float b1s[H_SZ];
  __shared__ float W2s[H_SZ];
  __shared__ float Wes[D_SZ * M1_SZ];  // c-major [c][m]
  __shared__ float bes[M1_SZ];
  __shared__ float ccws[S1];
  __shared__ float stepss[S1];
  __shared__ float misc[2];            // b2[d], exp(scaling[d])
  __shared__ float xs[BROWS * 36];     // x tile, row stride 36

  // ---- staging ----
  {
    const float* W1d = W1 + d * (M1_SZ + 1) * H_SZ;  // [i][h] row-major
    for (int idx = tid; idx < (M1_SZ + 1) * H_SZ; idx += BT) {
      int i = idx >> 6, h = idx & 63;  // coalesced global read
      W1t[h * 13 + i] = W1d[idx];      // transposed LDS write
    }
    if (tid < H_SZ) { b1s[tid] = b1[d * H_SZ + tid]; W2s[tid] = W2[d * H_SZ + tid]; }
    if (tid < M1_SZ) bes[tid] = be[tid * D_SZ + d];
    {
      int m = tid >> 5, c = tid & 31;
      Wes[c * M1_SZ + m] = We[(m * D_SZ + d) * D_SZ + c];
    }
    {  // x tile: 32 rows x 32 floats = 256 float4, one per thread
      const float4* xg = reinterpret_cast<const float4*>(x + (size_t)btile * D_SZ);
      int row = tid >> 3, c4 = tid & 7;
      *reinterpret_cast<float4*>(&xs[row * 36 + c4 * 4]) = xg[tid];
    }
    if (tid < S1) {  // fp32 Clenshaw-Curtis (threshold is lenient)
      stepss[tid] = cosf((float)tid * ((float)M_PI / 20.f));
      float acc = 0.f;
#pragma unroll
      for (int k = 0; k <= 10; ++k) {
        float w = (k == 0) ? 1.f : 2.f / (1.f - 4.f * (float)(k * k));
        float c = cosf((float)(k * tid) * ((float)M_PI / 10.f));
        float lam = (tid == 0 || tid == NSTEP) ? 0.5f * c : c;
        acc += w * lam;
      }
      ccws[tid] = 0.1f * acc;
    }
    if (tid == 0) { misc[0] = b2[d]; misc[1] = __expf(scaling[d]); }
  }
  __syncthreads();

  const int lane = tid & 63;
  const int hoct = (lane >> 3) & 7;                  // h-octant 0..7
  const int b_local = ((tid >> 6) << 3) | (lane & 7);
  const int b = btile + b_local;
  const float* xrow = &xs[b_local * 36];
  const float x0b = x0[(size_t)b * D_SZ + d];        // issue early

  // ---- masked encoder ----
  float a[M1_SZ];
#pragma unroll
  for (int m = 0; m < M1_SZ; ++m) a[m] = bes[m];
  for (int c = 0; c < d; ++c) {  // wave-uniform trip count
    float xc = xrow[c];
#pragma unroll
    for (int m = 0; m < M1_SZ; ++m) a[m] = fmaf(xc, Wes[c * M1_SZ + m], a[m]);
  }
  float hm[M1_SZ];
#pragma unroll
  for (int m = 0; m < M1_SZ; ++m) {  // tanh via exp2 + rcp
    float t = fast_exp2(a[m] * (2.f * LOG2E));
    hm[m] = 1.f - 2.f * fast_rcp(t + 1.f);
  }
  const float hm0 = hm[0];

  const float xb = xrow[d];
  const float dxe = xb - x0b;
  const float xc1 = 0.5f * dxe;
  const float xc1L = xc1 * LOG2E;
  const float xc0L = (x0b + xc1) * LOG2E;

  // ---- preload per-h constants (8 h per thread), then PIN them in VGPRs ----
  float baseL[HO], w1x[HO], w2h[HO];
  float w2sA = 0.f, w2sB = 0.f;
#pragma unroll
  for (int j = 0; j < HO; ++j) {
    const int hh = hoct * HO + j;
    const float* wrow = &W1t[hh * 13];
    float base = b1s[hh];
#pragma unroll
    for (int m = 0; m < M1_SZ; ++m) base = fmaf(hm[m], wrow[m + 1], base);
    baseL[j] = base * LOG2E;
    w1x[j] = wrow[0];
    w2h[j] = W2s[hh];
    pin(baseL[j]); pin(w1x[j]); pin(w2h[j]);  // block LDS-remat in the s-loop
    if (j & 1) w2sB += w2h[j]; else w2sA += w2h[j];
  }
  // fold elu "-1" and (octant 0 only) the b2 bias into the accumulator init
  const float acc0A = -w2sA + ((hoct == 0) ? misc[0] : 0.f);
  const float acc0B = -w2sB;

  // ---- fused main loop: per step, 8-h partial -> 3-level butterfly -> elu -> dzsum ----
  float dzsum = 0.f;
  for (int s = 0; s < S1; ++s) {
    const float XsL = fmaf(xc1L, stepss[s], xc0L);
    float accA = acc0A, accB = acc0B;
#pragma unroll
    for (int j = 0; j < HO; j += 2) {
      {
        float preL = fmaf(XsL, w1x[j], baseL[j]);
        float e = fmaf(fmaxf(preL, 0.f), LN2, fast_exp2(fminf(preL, 0.f)));
        accA = fmaf(e, w2h[j], accA);
      }
      {
        float preL = fmaf(XsL, w1x[j + 1], baseL[j + 1]);
        float e = fmaf(fmaxf(preL, 0.f), LN2, fast_exp2(fminf(preL, 0.f)));
        accB = fmaf(e, w2h[j + 1], accB);
      }
    }
    float acc = accA + accB;
    acc += __shfl_xor(acc, 8);
    acc += __shfl_xor(acc, 16);
    acc += __shfl_xor(acc, 32);
    float pL = acc * LOG2E;
    float dz = fmaf(fmaxf(pL, 0.f), LN2, fast_exp2(fminf(pL, 0.f)));  // elu+1
    dzsum = fmaf(ccws[s], dz, dzsum);
  }

  float z = fmaf(xc1, dzsum, hm0);  // z_int + z0
  if (hoct == 0) out[(size_t)b * D_SZ + d] = misc[1] * z;
}

extern "C" void kernel_launch(void* const* d_in, const int* in_sizes, int n_in,
                              void* d_out, int out_size, void* d_ws, size_t ws_size,
                              hipStream_t stream) {
  const float* x       = (const float*)d_in[0];
  const float* x0      = (const float*)d_in[1];
  const float* We      = (const float*)d_in[2];
  const float* be      = (const float*)d_in[3];
  const float* W1      = (const float*)d_in[4];
  const float* b1      = (const float*)d_in[5];
  const float* W2      = (const float*)d_in[6];
  const float* b2      = (const float*)d_in[7];
  const float* scaling = (const float*)d_in[8];
  float* out = (float*)d_out;

  dim3 grid(B_SZ / BROWS, D_SZ);
  umnn_main_kernel<<<grid, BT, 0, stream>>>(x, x0, We, be, W1, b1, W2, b2,
                                            scaling, out);
}

// Round 9
// 43.780 us; speedup vs baseline: 1.1693x; 1.1649x over previous
//
#include <hip/hip_runtime.h>
#include <math.h>

#define B_SZ 4096
#define D_SZ 32
#define M1_SZ 8
#define H_SZ 64
#define NSTEP 20
#define S1 21
#define BROWS 128  // rows per block
#define BT 256     // 4 waves; lane = [sgrp(1b)|b_lo(5b)]; wave covers 32 rows
#define KS 11      // steps per thread (sgrp0: s=0..10; sgrp1: s=11..21, 21 = dead slot)

#ifndef M_PI
#define M_PI 3.14159265358979323846
#endif

#define LOG2E 1.44269504088896340736f
#define LN2   0.69314718055994530942f

__device__ __forceinline__ float fast_exp2(float x) {
#if __has_builtin(__builtin_amdgcn_exp2f)
  return __builtin_amdgcn_exp2f(x);
#else
  return exp2f(x);
#endif
}
__device__ __forceinline__ float fast_rcp(float x) {
#if __has_builtin(__builtin_amdgcn_rcpf)
  return __builtin_amdgcn_rcpf(x);
#else
  return 1.0f / x;
#endif
}

__global__ __launch_bounds__(BT) void umnn_main_kernel(
    const float* __restrict__ x, const float* __restrict__ x0,
    const float* __restrict__ We, const float* __restrict__ be,
    const float* __restrict__ W1, const float* __restrict__ b1,
    const float* __restrict__ W2, const float* __restrict__ b2,
    const float* __restrict__ scaling, float* __restrict__ out) {
  const int btile = blockIdx.x * BROWS;
  const int d = blockIdx.y;  // block-uniform
  const int tid = threadIdx.x;

  // baseL[b_local][h], stride 66 (2-way banks). Staging-phase alias: xs[128][33].
  __shared__ __align__(16) float baseL[BROWS * 66];
  __shared__ __align__(16) float W1tp[H_SZ * 8];  // [h][m] = W1[d][m+1][h]
  __shared__ float b1s[H_SZ];
  __shared__ __align__(16) float w1xLs[H_SZ];    // W1[d][0][h] * LOG2E
  __shared__ __align__(16) float w2hs[H_SZ];     // W2[d][h]
  __shared__ float Wes[D_SZ * M1_SZ];            // [c][m]
  __shared__ float bes[M1_SZ];
  __shared__ float steps_ext[S1 + 1];            // [21] = 1.0 (dead slot)
  __shared__ float ccw_ext[S1 + 1];              // [21] = 0.0
  __shared__ float misc[4];                      // b2, exp(scaling), w2sum

  float* xs = baseL;  // stride 33; fully consumed before baseL is written

  // ---- staging ----
  {
    const float* W1d = W1 + d * (M1_SZ + 1) * H_SZ;
    {  // W1tp: 512 elems, 2 per thread; coalesced global reads
      int m = tid >> 6, h = tid & 63;
      W1tp[h * 8 + m] = W1d[(m + 1) * H_SZ + h];
      int idx = tid + 256; m = idx >> 6; h = idx & 63;
      W1tp[h * 8 + m] = W1d[(m + 1) * H_SZ + h];
    }
    if (tid < H_SZ) {
      b1s[tid] = b1[d * H_SZ + tid];
      w1xLs[tid] = W1d[tid] * LOG2E;
      w2hs[tid] = W2[d * H_SZ + tid];
    }
    if (tid < M1_SZ) bes[tid] = be[tid * D_SZ + d];
    { int m = tid >> 5, c = tid & 31; Wes[c * 8 + m] = We[(m * D_SZ + d) * D_SZ + c]; }
#pragma unroll
    for (int k = 0; k < 16; ++k) {  // x tile, scalar, stride 33 (conflict-free reads)
      int idx = tid + k * 256;
      int r = idx >> 5, c = idx & 31;
      xs[r * 33 + c] = x[(size_t)btile * D_SZ + idx];
    }
    if (tid < S1) {  // fp32 Clenshaw-Curtis (lenient threshold)
      steps_ext[tid] = cosf((float)tid * ((float)M_PI / 20.f));
      float acc = 0.f;
#pragma unroll
      for (int k = 0; k <= 10; ++k) {
        float w = (k == 0) ? 1.f : 2.f / (1.f - 4.f * (float)(k * k));
        float c = cosf((float)(k * tid) * ((float)M_PI / 10.f));
        float lam = (tid == 0 || tid == NSTEP) ? 0.5f * c : c;
        acc += w * lam;
      }
      ccw_ext[tid] = 0.1f * acc;
    }
    if (tid == 21) { steps_ext[21] = 1.f; ccw_ext[21] = 0.f; }
    if (tid == 0) { misc[0] = b2[d]; misc[1] = __expf(scaling[d]); }
  }
  __syncthreads();

  const int lane = tid & 63;
  const int b_lo = lane & 31;
  const int sgrp = lane >> 5;                    // 0: s 0..10, 1: s 11..21
  const int b_local = ((tid >> 6) << 5) | b_lo;  // 0..127
  const int b = btile + b_local;
  const float* xrow = &xs[b_local * 33];
  const float x0b = x0[(size_t)b * D_SZ + d];

  // ---- masked encoder (x2 redundancy per (b,d)) ----
  float a[M1_SZ];
#pragma unroll
  for (int m = 0; m < M1_SZ; ++m) a[m] = bes[m];
  for (int c = 0; c < d; ++c) {  // wave-uniform trip count
    float xc = xrow[c];
#pragma unroll
    for (int m = 0; m < M1_SZ; ++m) a[m] = fmaf(xc, Wes[c * 8 + m], a[m]);
  }
  float hm[M1_SZ];
#pragma unroll
  for (int m = 0; m < M1_SZ; ++m) {  // tanh via exp2 + rcp
    float t = fast_exp2(a[m] * (2.f * LOG2E));
    hm[m] = 1.f - 2.f * fast_rcp(t + 1.f);
  }
  const float hm0 = hm[0];

  const float xb = xrow[d];
  const float dxe = xb - x0b;
  const float xc1 = 0.5f * dxe;
  const float xc0 = x0b + xc1;

  const int sbase = sgrp * KS;
  float Xs[KS];  // natural-domain quadrature points for my steps
#pragma unroll
  for (int k = 0; k < KS; ++k) Xs[k] = fmaf(xc1, steps_ext[sbase + k], xc0);

  if (tid == 0) {  // block-uniform w2 sum (folds elu "-1")
    float s = 0.f;
#pragma unroll
    for (int h = 0; h < H_SZ; ++h) s += w2hs[h];
    misc[2] = s;
  }
  __syncthreads();  // all xs reads complete

  // ---- write baseL for my 32 h's (clobbers xs region) ----
#pragma unroll 4
  for (int j = 0; j < 32; ++j) {
    int h = sgrp * 32 + j;
    float4 w0 = *reinterpret_cast<float4*>(&W1tp[h * 8]);
    float4 w1v = *reinterpret_cast<float4*>(&W1tp[h * 8 + 4]);
    float bb = b1s[h];
    bb = fmaf(hm[0], w0.x, bb); bb = fmaf(hm[1], w0.y, bb);
    bb = fmaf(hm[2], w0.z, bb); bb = fmaf(hm[3], w0.w, bb);
    bb = fmaf(hm[4], w1v.x, bb); bb = fmaf(hm[5], w1v.y, bb);
    bb = fmaf(hm[6], w1v.z, bb); bb = fmaf(hm[7], w1v.w, bb);
    baseL[b_local * 66 + h] = bb * LOG2E;
  }
  __syncthreads();

  // ---- main loop: all 64 h, my 11 steps; no per-step cross-lane traffic ----
  const float acc0 = misc[0] - misc[2];  // b2 - sum(w2)
  float acc[KS];
#pragma unroll
  for (int k = 0; k < KS; ++k) acc[k] = acc0;

  const float* myBase = &baseL[b_local * 66];
#pragma unroll 2
  for (int hg = 0; hg < 16; ++hg) {
    float4 w1 = *reinterpret_cast<const float4*>(&w1xLs[hg * 4]);  // uniform: broadcast
    float4 w2 = *reinterpret_cast<const float4*>(&w2hs[hg * 4]);
    float2 ba = *reinterpret_cast<const float2*>(&myBase[hg * 4]);
    float2 bc = *reinterpret_cast<const float2*>(&myBase[hg * 4 + 2]);
    const float bse[4] = {ba.x, ba.y, bc.x, bc.y};
    const float w1a[4] = {w1.x, w1.y, w1.z, w1.w};
    const float w2a[4] = {w2.x, w2.y, w2.z, w2.w};
#pragma unroll
    for (int k = 0; k < KS; ++k) {
      float ak = acc[k];
#pragma unroll
      for (int hh = 0; hh < 4; ++hh) {
        float preL = fmaf(Xs[k], w1a[hh], bse[hh]);  // (base + w1x*X)*log2e
        float e = fmaf(fmaxf(preL, 0.f), LN2, fast_exp2(fminf(preL, 0.f)));
        ak = fmaf(e, w2a[hh], ak);
      }
      acc[k] = ak;
    }
  }

  // ---- per-step second elu + quadrature partial, then one shfl ----
  float dzsum = 0.f;
#pragma unroll
  for (int k = 0; k < KS; ++k) {
    float pL = acc[k] * LOG2E;
    float dz = fmaf(fmaxf(pL, 0.f), LN2, fast_exp2(fminf(pL, 0.f)));  // elu+1
    dzsum = fmaf(ccw_ext[sbase + k], dz, dzsum);
  }
  dzsum += __shfl_xor(dzsum, 32);  // combine the two step-halves

  if (sgrp == 0) out[(size_t)b * D_SZ + d] = misc[1] * fmaf(xc1, dzsum, hm0);
}

extern "C" void kernel_launch(void* const* d_in, const int* in_sizes, int n_in,
                              void* d_out, int out_size, void* d_ws, size_t ws_size,
                              hipStream_t stream) {
  const float* x       = (const float*)d_in[0];
  const float* x0      = (const float*)d_in[1];
  const float* We      = (const float*)d_in[2];
  const float* be      = (const float*)d_in[3];
  const float* W1      = (const float*)d_in[4];
  const float* b1      = (const float*)d_in[5];
  const float* W2      = (const float*)d_in[6];
  const float* b2      = (const float*)d_in[7];
  const float* scaling = (const float*)d_in[8];
  float* out = (float*)d_out;

  dim3 grid(B_SZ / BROWS, D_SZ);
  umnn_main_kernel<<<grid, BT, 0, stream>>>(x, x0, We, be, W1, b1, W2, b2,
                                            scaling, out);
}

// Round 10
// 43.371 us; speedup vs baseline: 1.1803x; 1.0094x over previous
//
#include <hip/hip_runtime.h>
#include <math.h>

#define B_SZ 4096
#define D_SZ 32
#define M1_SZ 8
#define H_SZ 64
#define NSTEP 20
#define S1 21
#define BROWS 64   // rows per block
#define BT 128     // 2 waves; lane = [sgrp(1b)|b_lo(5b)]; wave covers 32 rows x 2 sgrps
#define KS 11      // steps per thread (sgrp0: s=0..10; sgrp1: s=11..21, 21 = dead slot)

#ifndef M_PI
#define M_PI 3.14159265358979323846
#endif

#define LOG2E 1.44269504088896340736f
#define LN2   0.69314718055994530942f

__device__ __forceinline__ float fast_exp2(float x) {
#if __has_builtin(__builtin_amdgcn_exp2f)
  return __builtin_amdgcn_exp2f(x);
#else
  return exp2f(x);
#endif
}
__device__ __forceinline__ float fast_rcp(float x) {
#if __has_builtin(__builtin_amdgcn_rcpf)
  return __builtin_amdgcn_rcpf(x);
#else
  return 1.0f / x;
#endif
}

__global__ __launch_bounds__(BT) void umnn_main_kernel(
    const float* __restrict__ x, const float* __restrict__ x0,
    const float* __restrict__ We, const float* __restrict__ be,
    const float* __restrict__ W1, const float* __restrict__ b1,
    const float* __restrict__ W2, const float* __restrict__ b2,
    const float* __restrict__ scaling, float* __restrict__ out) {
  const int btile = blockIdx.x * BROWS;
  const int d = blockIdx.y;  // block-uniform
  const int tid = threadIdx.x;

  // Wpack[hg][slot]: slot0 = b1*L (4h), slot1 = w1x*L, slot2 = w2, slot3+m = W1[m+1]*L
  __shared__ __align__(16) float4 Wpack[16 * 11];  // 2816 B
  __shared__ float xs[BROWS * 33];                 // 8448 B, stride 33: conflict-free
  __shared__ float Wes[D_SZ * M1_SZ];              // [c][m], 1024 B
  __shared__ float bes[M1_SZ];
  __shared__ float steps_ext[S1 + 1];              // [21] = 1.0 (dead slot)
  __shared__ float ccw_ext[S1 + 1];                // [21] = 0.0
  __shared__ float misc[4];                        // b2, exp(scaling), w2sum

  // ---- staging ----
  {
    const float* W1d = W1 + d * (M1_SZ + 1) * H_SZ;  // [i][h] row-major
    if (tid < H_SZ) {  // one h per thread; all weights pre-scaled by LOG2E
      int hg = tid >> 2, j = tid & 3;
      float* Wf = reinterpret_cast<float*>(Wpack);
      Wf[(hg * 11 + 0) * 4 + j] = b1[d * H_SZ + tid] * LOG2E;
      Wf[(hg * 11 + 1) * 4 + j] = W1d[tid] * LOG2E;
      Wf[(hg * 11 + 2) * 4 + j] = W2[d * H_SZ + tid];
#pragma unroll
      for (int m = 0; m < M1_SZ; ++m)
        Wf[(hg * 11 + 3 + m) * 4 + j] = W1d[(m + 1) * H_SZ + tid] * LOG2E;
    }
    if (tid < M1_SZ) bes[tid] = be[tid * D_SZ + d];
    {
      int idx = tid;       int m = idx >> 5, c = idx & 31;
      Wes[c * 8 + m] = We[(m * D_SZ + d) * D_SZ + c];
      idx = tid + BT;      m = idx >> 5;  c = idx & 31;
      Wes[c * 8 + m] = We[(m * D_SZ + d) * D_SZ + c];
    }
#pragma unroll
    for (int k = 0; k < 16; ++k) {  // x tile, scalar, stride 33
      int idx = tid + k * BT;
      int r = idx >> 5, c = idx & 31;
      xs[r * 33 + c] = x[(size_t)btile * D_SZ + idx];
    }
    if (tid < S1) {  // fp32 Clenshaw-Curtis (lenient threshold)
      steps_ext[tid] = cosf((float)tid * ((float)M_PI / 20.f));
      float acc = 0.f;
#pragma unroll
      for (int k = 0; k <= 10; ++k) {
        float w = (k == 0) ? 1.f : 2.f / (1.f - 4.f * (float)(k * k));
        float c = cosf((float)(k * tid) * ((float)M_PI / 10.f));
        float lam = (tid == 0 || tid == NSTEP) ? 0.5f * c : c;
        acc += w * lam;
      }
      ccw_ext[tid] = 0.1f * acc;
    }
    if (tid == S1) { steps_ext[S1] = 1.f; ccw_ext[S1] = 0.f; }
    if (tid == 0) { misc[0] = b2[d]; misc[1] = __expf(scaling[d]); }
  }
  __syncthreads();

  if (tid == 0) {  // block-uniform sum(w2) (folds the elu "-1")
    const float* Wf = reinterpret_cast<const float*>(Wpack);
    float s = 0.f;
#pragma unroll
    for (int hg = 0; hg < 16; ++hg) {
      const float* w2p = &Wf[(hg * 11 + 2) * 4];
      s += w2p[0] + w2p[1] + w2p[2] + w2p[3];
    }
    misc[2] = s;
  }

  const int lane = tid & 63;
  const int b_lo = lane & 31;
  const int sgrp = lane >> 5;                    // 0: s 0..10, 1: s 11..21
  const int b_local = ((tid >> 6) << 5) | b_lo;  // 0..63
  const int b = btile + b_local;
  const float* xrow = &xs[b_local * 33];
  const float x0b = x0[(size_t)b * D_SZ + d];

  // ---- masked encoder (x2 redundancy across sgrp) ----
  float a[M1_SZ];
#pragma unroll
  for (int m = 0; m < M1_SZ; ++m) a[m] = bes[m];
  for (int c = 0; c < d; ++c) {  // wave-uniform trip count
    float xc = xrow[c];
#pragma unroll
    for (int m = 0; m < M1_SZ; ++m) a[m] = fmaf(xc, Wes[c * 8 + m], a[m]);
  }
  float hm[M1_SZ];
#pragma unroll
  for (int m = 0; m < M1_SZ; ++m) {  // tanh via exp2 + rcp
    float t = fast_exp2(a[m] * (2.f * LOG2E));
    hm[m] = 1.f - 2.f * fast_rcp(t + 1.f);
  }
  const float hm0 = hm[0];

  const float xb = xrow[d];
  const float dxe = xb - x0b;
  const float xc1 = 0.5f * dxe;
  const float xc0 = x0b + xc1;

  const int sbase = sgrp * KS;
  float Xs[KS];  // natural domain (weights carry the LOG2E)
#pragma unroll
  for (int k = 0; k < KS; ++k) Xs[k] = fmaf(xc1, steps_ext[sbase + k], xc0);

  __syncthreads();  // misc[2] visible

  // ---- main loop: all 64 h (base recomputed per 4-h group), my 11 steps ----
  const float acc0 = misc[0] - misc[2];  // b2 - sum(w2)
  float acc[KS];
#pragma unroll
  for (int k = 0; k < KS; ++k) acc[k] = acc0;

  for (int hg = 0; hg < 16; ++hg) {
    const float4* blk = &Wpack[hg * 11];
    float4 bse = blk[0];   // b1*L
    float4 w1v = blk[1];   // w1x*L
    float4 w2v = blk[2];   // w2 (natural)
#pragma unroll
    for (int m = 0; m < M1_SZ; ++m) {  // base += hm[m] * W1[m+1]*L
      float4 wm = blk[3 + m];
      bse.x = fmaf(hm[m], wm.x, bse.x);
      bse.y = fmaf(hm[m], wm.y, bse.y);
      bse.z = fmaf(hm[m], wm.z, bse.z);
      bse.w = fmaf(hm[m], wm.w, bse.w);
    }
    const float bsa[4] = {bse.x, bse.y, bse.z, bse.w};
    const float w1a[4] = {w1v.x, w1v.y, w1v.z, w1v.w};
    const float w2a[4] = {w2v.x, w2v.y, w2v.z, w2v.w};
#pragma unroll
    for (int k = 0; k < KS; ++k) {
      float ak = acc[k];
#pragma unroll
      for (int j = 0; j < 4; ++j) {
        float preL = fmaf(Xs[k], w1a[j], bsa[j]);  // log2-domain preact
        float e = fmaf(fmaxf(preL, 0.f), LN2, fast_exp2(fminf(preL, 0.f)));  // elu+1
        ak = fmaf(e, w2a[j], ak);
      }
      acc[k] = ak;
    }
  }

  // ---- per-step second elu + quadrature partial, then one shfl ----
  float dzsum = 0.f;
#pragma unroll
  for (int k = 0; k < KS; ++k) {
    float pL = acc[k] * LOG2E;
    float dz = fmaf(fmaxf(pL, 0.f), LN2, fast_exp2(fminf(pL, 0.f)));  // elu+1
    dzsum = fmaf(ccw_ext[sbase + k], dz, dzsum);
  }
  dzsum += __shfl_xor(dzsum, 32);  // combine the two step-halves

  if (sgrp == 0) out[(size_t)b * D_SZ + d] = misc[1] * fmaf(xc1, dzsum, hm0);
}

extern "C" void kernel_launch(void* const* d_in, const int* in_sizes, int n_in,
                              void* d_out, int out_size, void* d_ws, size_t ws_size,
                              hipStream_t stream) {
  const float* x       = (const float*)d_in[0];
  const float* x0      = (const float*)d_in[1];
  const float* We      = (const float*)d_in[2];
  const float* be      = (const float*)d_in[3];
  const float* W1      = (const float*)d_in[4];
  const float* b1      = (const float*)d_in[5];
  const float* W2      = (const float*)d_in[6];
  const float* b2      = (const float*)d_in[7];
  const float* scaling = (const float*)d_in[8];
  float* out = (float*)d_out;

  dim3 grid(B_SZ / BROWS, D_SZ);
  umnn_main_kernel<<<grid, BT, 0, stream>>>(x, x0, We, be, W1, b1, W2, b2,
                                            scaling, out);
}